// Round 2
// baseline (9274.150 us; speedup 1.0000x reference)
//
#include <hip/hip_runtime.h>
#include <hip/hip_bf16.h>
#include <math.h>

#define NTOK 16384   // N = B*C
#define DH   1024    // D = H = EH = TH
#define NE   6       // experts
#define NT   3       // tasks

// ---------------------------------------------------------------------------
// Tiled 64x64 GEMM core: acc[4][4] += A[n0:n0+64, :K] @ B[:K, m0:m0+64]
// 256 threads, 4x4 micro-tile per thread. ACC = float or double.
// A is the chunk-local base (row stride K).
// ---------------------------------------------------------------------------
template<typename ACC>
__device__ __forceinline__ void mm_tile(const float* __restrict__ A,
                                        const float* __restrict__ B,
                                        int K, int M, int n0, int m0,
                                        ACC acc[4][4])
{
    __shared__ float As[16][64];   // [k][n]
    __shared__ float Bs[16][64];   // [k][m]
    const int tid  = threadIdx.x;
    const int tx   = tid & 15;         // col group
    const int ty   = tid >> 4;         // row group
    const int la_n = tid >> 2;         // 0..63
    const int la_k = (tid & 3) << 2;   // 0,4,8,12
    const int lb_k = tid >> 4;         // 0..15
    const int lb_m = (tid & 15) << 2;  // 0..60

    for (int kc = 0; kc < K; kc += 16) {
        float4 av = *(const float4*)(A + (long)(n0 + la_n) * K + (kc + la_k));
        float4 bv = *(const float4*)(B + (long)(kc + lb_k) * M + (m0 + lb_m));
        __syncthreads();
        As[la_k + 0][la_n] = av.x;
        As[la_k + 1][la_n] = av.y;
        As[la_k + 2][la_n] = av.z;
        As[la_k + 3][la_n] = av.w;
        *(float4*)(&Bs[lb_k][lb_m]) = bv;
        __syncthreads();
#pragma unroll
        for (int k = 0; k < 16; ++k) {
            float4 a4 = *(const float4*)(&As[k][ty << 2]);
            float4 b4 = *(const float4*)(&Bs[k][tx << 2]);
            const float aa[4] = {a4.x, a4.y, a4.z, a4.w};
            const float bb[4] = {b4.x, b4.y, b4.z, b4.w};
#pragma unroll
            for (int i = 0; i < 4; ++i)
#pragma unroll
                for (int j = 0; j < 4; ++j)
                    acc[i][j] += (ACC)aa[i] * (ACC)bb[j];
        }
    }
}

// ---------------------------------------------------------------------------
// C = op(A@B + bias), op = relu or identity.  [chunk x K] @ [K x M]
// ---------------------------------------------------------------------------
template<typename ACC, bool RELU>
__global__ __launch_bounds__(256) void k_gemm_bias(const float* __restrict__ A,
                                                   const float* __restrict__ B,
                                                   const float* __restrict__ bias,
                                                   float* __restrict__ C,
                                                   int K, int M)
{
    ACC acc[4][4] = {};
    const int n0 = blockIdx.x * 64, m0 = blockIdx.y * 64;
    mm_tile<ACC>(A, B, K, M, n0, m0, acc);
    const int tx = threadIdx.x & 15, ty = threadIdx.x >> 4;
#pragma unroll
    for (int i = 0; i < 4; ++i) {
        const int r = n0 + (ty << 2) + i;
#pragma unroll
        for (int j = 0; j < 4; ++j) {
            const int c = m0 + (tx << 2) + j;
            float v = (float)(acc[i][j] + (ACC)bias[c]);
            if (RELU) v = fmaxf(v, 0.0f);
            C[(long)r * M + c] = v;
        }
    }
}

// ---------------------------------------------------------------------------
// Expert layer 2 + gated combine (chunk-local):
//   eo = A@B + eb2[e];  mo[t][r][:] (+)= gates[e][t][r] * eo[r][:]
// Experts are launched sequentially -> no race on mo.
// ---------------------------------------------------------------------------
__global__ __launch_bounds__(256) void k_gemm_combine(const float* __restrict__ A,
                                                      const float* __restrict__ B,
                                                      const float* __restrict__ bias,
                                                      const float* __restrict__ gates, // [E][T][chunk]
                                                      float* __restrict__ mo,          // [T][chunk][DH]
                                                      int e, int first, int chunk)
{
    float acc[4][4] = {};
    const int n0 = blockIdx.x * 64, m0 = blockIdx.y * 64;
    mm_tile<float>(A, B, DH, DH, n0, m0, acc);
    const int tx = threadIdx.x & 15, ty = threadIdx.x >> 4;
#pragma unroll
    for (int i = 0; i < 4; ++i) {
        const int r = n0 + (ty << 2) + i;
        const float g0 = gates[(long)(e * NT + 0) * chunk + r];
        const float g1 = gates[(long)(e * NT + 1) * chunk + r];
        const float g2 = gates[(long)(e * NT + 2) * chunk + r];
#pragma unroll
        for (int j = 0; j < 4; ++j) {
            const int c = m0 + (tx << 2) + j;
            const float v = acc[i][j] + bias[c];
            const long o0 = ((long)0 * chunk + r) * DH + c;
            const long o1 = ((long)1 * chunk + r) * DH + c;
            const long o2 = ((long)2 * chunk + r) * DH + c;
            if (first) {
                mo[o0] = g0 * v;
                mo[o1] = g1 * v;
                mo[o2] = g2 * v;
            } else {
                mo[o0] += g0 * v;
                mo[o1] += g1 * v;
                mo[o2] += g2 * v;
            }
        }
    }
}

// ---------------------------------------------------------------------------
// Tower: th = relu(mo[t]@tw1[t] + tb1[t]); out[t][n_base+r] += th . tw2[t]
// Fused dot via 16-lane shuffle reduce + atomicAdd (out pre-init to tb2[t]).
// ---------------------------------------------------------------------------
__global__ __launch_bounds__(256) void k_gemm_tower(const float* __restrict__ mo,
                                                    const float* __restrict__ tw1,
                                                    const float* __restrict__ tb1,
                                                    const float* __restrict__ tw2,
                                                    float* __restrict__ out,
                                                    int n_base, int chunk)
{
    const int t = blockIdx.z;
    const float* A  = mo  + (long)t * chunk * DH;
    const float* Bm = tw1 + (long)t * DH * DH;
    const float* b1 = tb1 + t * DH;
    const float* w2 = tw2 + t * DH;

    float acc[4][4] = {};
    const int n0 = blockIdx.x * 64, m0 = blockIdx.y * 64;
    mm_tile<float>(A, Bm, DH, DH, n0, m0, acc);
    const int tx = threadIdx.x & 15, ty = threadIdx.x >> 4;

    float s[4];
#pragma unroll
    for (int i = 0; i < 4; ++i) {
        s[i] = 0.0f;
#pragma unroll
        for (int j = 0; j < 4; ++j) {
            const int c = m0 + (tx << 2) + j;
            float v = fmaxf(acc[i][j] + b1[c], 0.0f);
            s[i] += v * w2[c];
        }
    }
    // reduce across the 16 tx lanes (each 16-lane segment shares ty)
#pragma unroll
    for (int d = 8; d > 0; d >>= 1)
#pragma unroll
        for (int i = 0; i < 4; ++i)
            s[i] += __shfl_down(s[i], d, 16);
    if (tx == 0) {
#pragma unroll
        for (int i = 0; i < 4; ++i)
            atomicAdd(out + (long)t * NTOK + n_base + n0 + (ty << 2) + i, s[i]);
    }
}

// ---------------------------------------------------------------------------
// Gating (chunk-local): logits[t,r,e] = h[r,:] . w_gate[t,:,e] in fp64
// (exact top-k match vs reference), then top-3 + softmax -> gates[e][t][r].
// ---------------------------------------------------------------------------
__global__ __launch_bounds__(256) void k_gating(const float* __restrict__ h,
                                                const float* __restrict__ w_gate, // [T][DH][E]
                                                float* __restrict__ gates,        // [E][T][chunk]
                                                int chunk)
{
    __shared__ float hs[64][17];
    const int tid = threadIdx.x;
    const int n0  = blockIdx.x * 64;
    const int t   = tid >> 6;    // 0..3 (3 = loader-only)
    const int nl  = tid & 63;
    const int la_n = tid >> 2;
    const int la_k = (tid & 3) << 2;

    double acc[NE] = {0, 0, 0, 0, 0, 0};
    for (int kc = 0; kc < DH; kc += 16) {
        float4 hv = *(const float4*)(h + (long)(n0 + la_n) * DH + kc + la_k);
        __syncthreads();
        hs[la_n][la_k + 0] = hv.x;
        hs[la_n][la_k + 1] = hv.y;
        hs[la_n][la_k + 2] = hv.z;
        hs[la_n][la_k + 3] = hv.w;
        __syncthreads();
        if (t < NT) {
            for (int k = 0; k < 16; ++k) {
                const double hvk = (double)hs[nl][k];
                const float* wg = w_gate + ((long)t * DH + kc + k) * NE;
#pragma unroll
                for (int e = 0; e < NE; ++e)
                    acc[e] += hvk * (double)wg[e];
            }
        }
    }
    if (t < NT) {
        bool used[NE] = {false, false, false, false, false, false};
        int idx[3];
        double tv[3];
#pragma unroll
        for (int k = 0; k < 3; ++k) {
            int best = -1;
#pragma unroll
            for (int e = 0; e < NE; ++e)
                if (!used[e] && (best < 0 || acc[e] > acc[best])) best = e;
            used[best] = true;
            idx[k] = best;
            tv[k] = acc[best];
        }
        const double m  = tv[0];
        const double w0 = exp(tv[0] - m), w1 = exp(tv[1] - m), w2 = exp(tv[2] - m);
        const double sum = w0 + w1 + w2;
        float g[NE] = {0.f, 0.f, 0.f, 0.f, 0.f, 0.f};
        g[idx[0]] = (float)(w0 / sum);
        g[idx[1]] = (float)(w1 / sum);
        g[idx[2]] = (float)(w2 / sum);
#pragma unroll
        for (int e = 0; e < NE; ++e)
            gates[(long)(e * NT + t) * chunk + n0 + nl] = g[e];
    }
}

__global__ __launch_bounds__(256) void k_init_out(float* __restrict__ out,
                                                  const float* __restrict__ tb2)
{
    const int i = blockIdx.x * 256 + threadIdx.x;
    if (i < NT * NTOK) out[i] = tb2[i >> 14];   // i / NTOK
}

// ---------------------------------------------------------------------------
extern "C" void kernel_launch(void* const* d_in, const int* in_sizes, int n_in,
                              void* d_out, int out_size, void* d_ws, size_t ws_size,
                              hipStream_t stream)
{
    const float* x      = (const float*)d_in[0];   // [N, D]
    const float* fc1_w  = (const float*)d_in[1];   // [D, H]
    const float* fc1_b  = (const float*)d_in[2];
    const float* fc2_w  = (const float*)d_in[3];
    const float* fc2_b  = (const float*)d_in[4];
    const float* w_gate = (const float*)d_in[5];   // [T, H, E]
    const float* ew1    = (const float*)d_in[6];   // [E, H, EH]
    const float* eb1    = (const float*)d_in[7];
    const float* ew2    = (const float*)d_in[8];   // [E, EH, H]
    const float* eb2    = (const float*)d_in[9];
    const float* tw1    = (const float*)d_in[10];  // [T, H, TH]
    const float* tb1    = (const float*)d_in[11];
    const float* tw2    = (const float*)d_in[12];  // [T, TH]
    const float* tb2    = (const float*)d_in[13];
    float* out = (float*)d_out;

    // Pick the largest chunk whose working set fits ws_size.
    // Per-token bytes: eh(DH) + h(DH) + mo(3*DH) floats + gates(NE*NT) floats.
    int chunk = 16384;
    while (chunk > 64) {
        size_t need = (size_t)chunk * (5u * DH * 4u + NE * NT * 4u);
        if (need <= ws_size) break;
        chunk >>= 1;
    }

    float* ws    = (float*)d_ws;
    float* ehb   = ws;                                // chunk*DH : h1, then per-expert eh
    float* h     = ehb + (size_t)chunk * DH;          // chunk*DH
    float* mo    = h   + (size_t)chunk * DH;          // 3*chunk*DH [T][chunk][DH]
    float* gates = mo  + (size_t)NT * chunk * DH;     // NE*NT*chunk

    const dim3 blk(256);
    const dim3 g2(chunk / 64, DH / 64);

    k_init_out<<<dim3((NT * NTOK + 255) / 256), blk, 0, stream>>>(out, tb2);

    for (int nb = 0; nb < NTOK; nb += chunk) {
        const float* xc = x + (size_t)nb * DH;

        // shared bottom (fp64 accumulate: gating-selection accuracy)
        k_gemm_bias<double, true ><<<g2, blk, 0, stream>>>(xc,  fc1_w, fc1_b, ehb, DH, DH);
        k_gemm_bias<double, false><<<g2, blk, 0, stream>>>(ehb, fc2_w, fc2_b, h,   DH, DH);

        // gating
        k_gating<<<dim3(chunk / 64), blk, 0, stream>>>(h, w_gate, gates, chunk);

        // experts (serialized -> race-free mo accumulate, single eh buffer)
        for (int e = 0; e < NE; ++e) {
            k_gemm_bias<float, true><<<g2, blk, 0, stream>>>(
                h, ew1 + (size_t)e * DH * DH, eb1 + e * DH, ehb, DH, DH);
            k_gemm_combine<<<g2, blk, 0, stream>>>(
                ehb, ew2 + (size_t)e * DH * DH, eb2 + e * DH, gates, mo, e,
                (e == 0) ? 1 : 0, chunk);
        }

        // towers + fused final dot
        k_gemm_tower<<<dim3(chunk / 64, DH / 64, NT), blk, 0, stream>>>(
            mo, tw1, tb1, tw2, out, nb, chunk);
    }
}

// Round 3
// 3244.400 us; speedup vs baseline: 2.8585x; 2.8585x over previous
//
#include <hip/hip_runtime.h>
#include <hip/hip_bf16.h>
#include <math.h>
#include <stdint.h>

#define NTOK 16384   // N = B*C
#define DH   1024    // D = H = EH = TH
#define NE   6       // experts
#define NT   3       // tasks

typedef _Float16 f16x8 __attribute__((ext_vector_type(8)));
typedef float    f32x4 __attribute__((ext_vector_type(4)));

// ---------------------------------------------------------------------------
// fp16 MFMA 128x128 tile core. A [rows x DH] row-major fp16 (token rows),
// Bt [M x DH] row-major fp16 (weights pre-transposed: row = output col).
// Block = 256 thr = 4 waves in 2x2; each wave = 64x64 via 4x4 of 16x16x32.
// Staging via global_load_lds width-16 (wave-uniform LDS base + lane*16).
// ---------------------------------------------------------------------------
__device__ __forceinline__ void stage16(const _Float16* g, _Float16* lds_base, int lane)
{
#if __has_builtin(__builtin_amdgcn_global_load_lds)
    __builtin_amdgcn_global_load_lds(
        (const __attribute__((address_space(1))) unsigned int*)(uintptr_t)g,
        (__attribute__((address_space(3))) unsigned int*)(uintptr_t)lds_base, 16, 0, 0);
#else
    *(float4*)(lds_base + lane * 8) = *(const float4*)g;
#endif
}

__device__ __forceinline__ f32x4 mfma16(f16x8 a, f16x8 b, f32x4 c)
{
    return __builtin_amdgcn_mfma_f32_16x16x32_f16(a, b, c, 0, 0, 0);
}

__device__ __forceinline__ void mfma_tile(const _Float16* __restrict__ A,
                                          const _Float16* __restrict__ Bt,
                                          int n0, int m0, f32x4 acc[4][4])
{
    __shared__ __align__(16) _Float16 As[128 * 32];
    __shared__ __align__(16) _Float16 Bs[128 * 32];
    const int tid  = threadIdx.x;
    const int w    = tid >> 6, lane = tid & 63;
    const int lr   = lane >> 2;            // staging row within 16-row group
    const int lk   = (lane & 3) * 8;       // fp16 offset within 32-k row
    const int wm   = (w >> 1) * 64, wn = (w & 1) * 64;
    const int fl   = lane & 15;            // m (A) / n (B) / col (D)
    const int fq   = (lane >> 4) * 8;      // k-octet

    const _Float16* ga0 = A  + (size_t)(n0 + w * 32 + lr) * DH + lk;
    const _Float16* ga1 = ga0 + 16 * DH;
    const _Float16* gb0 = Bt + (size_t)(m0 + w * 32 + lr) * DH + lk;
    const _Float16* gb1 = gb0 + 16 * DH;
    _Float16* la0 = As + (w * 32) * 32;
    _Float16* la1 = la0 + 16 * 32;
    _Float16* lb0 = Bs + (w * 32) * 32;
    _Float16* lb1 = lb0 + 16 * 32;

    for (int ks = 0; ks < DH; ks += 32) {
        __syncthreads();                       // LDS free from previous slab
        stage16(ga0 + ks, la0, lane);
        stage16(ga1 + ks, la1, lane);
        stage16(gb0 + ks, lb0, lane);
        stage16(gb1 + ks, lb1, lane);
        __syncthreads();                       // drains vmcnt -> LDS valid
        f16x8 af[4], bf[4];
#pragma unroll
        for (int i = 0; i < 4; ++i)
            af[i] = *(const f16x8*)(As + (wm + i * 16 + fl) * 32 + fq);
#pragma unroll
        for (int j = 0; j < 4; ++j)
            bf[j] = *(const f16x8*)(Bs + (wn + j * 16 + fl) * 32 + fq);
#pragma unroll
        for (int i = 0; i < 4; ++i)
#pragma unroll
            for (int j = 0; j < 4; ++j)
                acc[i][j] = mfma16(af[i], bf[j], acc[i][j]);
    }
}

// C/D layout: col = wn + j*16 + (lane&15); row = wm + i*16 + (lane>>4)*4 + reg.

// ---------------------------------------------------------------------------
// Expert layer 1: C16 = fp16(relu(A@Bt^T + bias)), C [rows x DH] fp16
// ---------------------------------------------------------------------------
__global__ __launch_bounds__(256) void k_mfma_h16relu(const _Float16* __restrict__ A,
                                                      const _Float16* __restrict__ Bt,
                                                      const float* __restrict__ bias,
                                                      _Float16* __restrict__ C)
{
    f32x4 acc[4][4] = {};
    const int n0 = blockIdx.x * 128, m0 = blockIdx.y * 128;
    mfma_tile(A, Bt, n0, m0, acc);
    const int lane = threadIdx.x & 63, w = threadIdx.x >> 6;
    const int wm = (w >> 1) * 64, wn = (w & 1) * 64;
    const int fl = lane & 15, quad = lane >> 4;
#pragma unroll
    for (int i = 0; i < 4; ++i)
#pragma unroll
        for (int reg = 0; reg < 4; ++reg) {
            const int r = n0 + wm + i * 16 + quad * 4 + reg;
#pragma unroll
            for (int j = 0; j < 4; ++j) {
                const int c = m0 + wn + j * 16 + fl;
                C[(size_t)r * DH + c] = (_Float16)fmaxf(acc[i][j][reg] + bias[c], 0.0f);
            }
        }
}

// ---------------------------------------------------------------------------
// Expert layer 2 + gated combine into fp16 mo (experts serialized -> no race)
// ---------------------------------------------------------------------------
__global__ __launch_bounds__(256) void k_mfma_combine(const _Float16* __restrict__ A,
                                                      const _Float16* __restrict__ Bt,
                                                      const float* __restrict__ bias,
                                                      const float* __restrict__ gates, // [E][T][chunk]
                                                      _Float16* __restrict__ mo,       // [T][chunk][DH]
                                                      int e, int first, int chunk)
{
    f32x4 acc[4][4] = {};
    const int n0 = blockIdx.x * 128, m0 = blockIdx.y * 128;
    mfma_tile(A, Bt, n0, m0, acc);
    const int lane = threadIdx.x & 63, w = threadIdx.x >> 6;
    const int wm = (w >> 1) * 64, wn = (w & 1) * 64;
    const int fl = lane & 15, quad = lane >> 4;
#pragma unroll
    for (int i = 0; i < 4; ++i)
#pragma unroll
        for (int reg = 0; reg < 4; ++reg) {
            const int r = n0 + wm + i * 16 + quad * 4 + reg;
            const float g0 = gates[(size_t)(e * NT + 0) * chunk + r];
            const float g1 = gates[(size_t)(e * NT + 1) * chunk + r];
            const float g2 = gates[(size_t)(e * NT + 2) * chunk + r];
#pragma unroll
            for (int j = 0; j < 4; ++j) {
                const int c = m0 + wn + j * 16 + fl;
                const float v = acc[i][j][reg] + bias[c];
                const size_t o0 = ((size_t)0 * chunk + r) * DH + c;
                const size_t o1 = ((size_t)1 * chunk + r) * DH + c;
                const size_t o2 = ((size_t)2 * chunk + r) * DH + c;
                if (first) {
                    mo[o0] = (_Float16)(g0 * v);
                    mo[o1] = (_Float16)(g1 * v);
                    mo[o2] = (_Float16)(g2 * v);
                } else {
                    mo[o0] = (_Float16)((float)mo[o0] + g0 * v);
                    mo[o1] = (_Float16)((float)mo[o1] + g1 * v);
                    mo[o2] = (_Float16)((float)mo[o2] + g2 * v);
                }
            }
        }
}

// ---------------------------------------------------------------------------
// Tower: th = relu(mo[t]@tw1t[t]^T + tb1[t]); out[t][n] += th . tw2[t]
// ---------------------------------------------------------------------------
__global__ __launch_bounds__(256) void k_mfma_tower(const _Float16* __restrict__ mo,
                                                    const _Float16* __restrict__ tw1t,
                                                    const float* __restrict__ tb1,
                                                    const float* __restrict__ tw2,
                                                    float* __restrict__ out,
                                                    int n_base, int chunk)
{
    const int t = blockIdx.z;
    const _Float16* A  = mo   + (size_t)t * chunk * DH;
    const _Float16* Bt = tw1t + (size_t)t * DH * DH;
    const float* b1 = tb1 + t * DH;
    const float* w2 = tw2 + t * DH;

    f32x4 acc[4][4] = {};
    const int n0 = blockIdx.x * 128, m0 = blockIdx.y * 128;
    mfma_tile(A, Bt, n0, m0, acc);
    const int lane = threadIdx.x & 63, w = threadIdx.x >> 6;
    const int wm = (w >> 1) * 64, wn = (w & 1) * 64;
    const int fl = lane & 15, quad = lane >> 4;

    float s[4][4];   // [i][reg]
#pragma unroll
    for (int i = 0; i < 4; ++i)
#pragma unroll
        for (int reg = 0; reg < 4; ++reg) {
            float v = 0.0f;
#pragma unroll
            for (int j = 0; j < 4; ++j) {
                const int c = m0 + wn + j * 16 + fl;
                v += fmaxf(acc[i][j][reg] + b1[c], 0.0f) * w2[c];
            }
            s[i][reg] = v;
        }
    // reduce the 16 lanes of each quad (same rows, different cols)
#pragma unroll
    for (int d = 8; d > 0; d >>= 1)
#pragma unroll
        for (int i = 0; i < 4; ++i)
#pragma unroll
            for (int reg = 0; reg < 4; ++reg)
                s[i][reg] += __shfl_down(s[i][reg], d, 16);
    if (fl == 0) {
#pragma unroll
        for (int i = 0; i < 4; ++i)
#pragma unroll
            for (int reg = 0; reg < 4; ++reg) {
                const int r = n0 + wm + i * 16 + quad * 4 + reg;
                atomicAdd(out + (size_t)t * NTOK + n_base + r, s[i][reg]);
            }
    }
}

// ---------------------------------------------------------------------------
// fp64-accumulated 64x64 fp32 GEMM (shared bottom; selection-exact) — as R2.
// ---------------------------------------------------------------------------
template<typename ACC>
__device__ __forceinline__ void mm_tile(const float* __restrict__ A,
                                        const float* __restrict__ B,
                                        int K, int M, int n0, int m0,
                                        ACC acc[4][4])
{
    __shared__ float As[16][64];
    __shared__ float Bs[16][64];
    const int tid  = threadIdx.x;
    const int tx   = tid & 15, ty = tid >> 4;
    const int la_n = tid >> 2, la_k = (tid & 3) << 2;
    const int lb_k = tid >> 4, lb_m = (tid & 15) << 2;

    for (int kc = 0; kc < K; kc += 16) {
        float4 av = *(const float4*)(A + (size_t)(n0 + la_n) * K + (kc + la_k));
        float4 bv = *(const float4*)(B + (size_t)(kc + lb_k) * M + (m0 + lb_m));
        __syncthreads();
        As[la_k + 0][la_n] = av.x;
        As[la_k + 1][la_n] = av.y;
        As[la_k + 2][la_n] = av.z;
        As[la_k + 3][la_n] = av.w;
        *(float4*)(&Bs[lb_k][lb_m]) = bv;
        __syncthreads();
#pragma unroll
        for (int k = 0; k < 16; ++k) {
            float4 a4 = *(const float4*)(&As[k][ty << 2]);
            float4 b4 = *(const float4*)(&Bs[k][tx << 2]);
            const float aa[4] = {a4.x, a4.y, a4.z, a4.w};
            const float bb[4] = {b4.x, b4.y, b4.z, b4.w};
#pragma unroll
            for (int i = 0; i < 4; ++i)
#pragma unroll
                for (int j = 0; j < 4; ++j)
                    acc[i][j] += (ACC)aa[i] * (ACC)bb[j];
        }
    }
}

template<typename ACC, bool RELU>
__global__ __launch_bounds__(256) void k_gemm_bias(const float* __restrict__ A,
                                                   const float* __restrict__ B,
                                                   const float* __restrict__ bias,
                                                   float* __restrict__ C,
                                                   int K, int M)
{
    ACC acc[4][4] = {};
    const int n0 = blockIdx.x * 64, m0 = blockIdx.y * 64;
    mm_tile<ACC>(A, B, K, M, n0, m0, acc);
    const int tx = threadIdx.x & 15, ty = threadIdx.x >> 4;
#pragma unroll
    for (int i = 0; i < 4; ++i) {
        const int r = n0 + (ty << 2) + i;
#pragma unroll
        for (int j = 0; j < 4; ++j) {
            const int c = m0 + (tx << 2) + j;
            float v = (float)(acc[i][j] + (ACC)bias[c]);
            if (RELU) v = fmaxf(v, 0.0f);
            C[(size_t)r * M + c] = v;
        }
    }
}

// ---------------------------------------------------------------------------
// Gating (fp64, selection-exact) — as R2.
// ---------------------------------------------------------------------------
__global__ __launch_bounds__(256) void k_gating(const float* __restrict__ h,
                                                const float* __restrict__ w_gate,
                                                float* __restrict__ gates,
                                                int chunk)
{
    __shared__ float hs[64][17];
    const int tid = threadIdx.x;
    const int n0  = blockIdx.x * 64;
    const int t   = tid >> 6;
    const int nl  = tid & 63;
    const int la_n = tid >> 2;
    const int la_k = (tid & 3) << 2;

    double acc[NE] = {0, 0, 0, 0, 0, 0};
    for (int kc = 0; kc < DH; kc += 16) {
        float4 hv = *(const float4*)(h + (size_t)(n0 + la_n) * DH + kc + la_k);
        __syncthreads();
        hs[la_n][la_k + 0] = hv.x;
        hs[la_n][la_k + 1] = hv.y;
        hs[la_n][la_k + 2] = hv.z;
        hs[la_n][la_k + 3] = hv.w;
        __syncthreads();
        if (t < NT) {
            for (int k = 0; k < 16; ++k) {
                const double hvk = (double)hs[nl][k];
                const float* wg = w_gate + ((size_t)t * DH + kc + k) * NE;
#pragma unroll
                for (int e = 0; e < NE; ++e)
                    acc[e] += hvk * (double)wg[e];
            }
        }
    }
    if (t < NT) {
        bool used[NE] = {false, false, false, false, false, false};
        int idx[3];
        double tv[3];
#pragma unroll
        for (int k = 0; k < 3; ++k) {
            int best = -1;
#pragma unroll
            for (int e = 0; e < NE; ++e)
                if (!used[e] && (best < 0 || acc[e] > acc[best])) best = e;
            used[best] = true;
            idx[k] = best;
            tv[k] = acc[best];
        }
        const double m  = tv[0];
        const double w0 = exp(tv[0] - m), w1 = exp(tv[1] - m), w2 = exp(tv[2] - m);
        const double sum = w0 + w1 + w2;
        float g[NE] = {0.f, 0.f, 0.f, 0.f, 0.f, 0.f};
        g[idx[0]] = (float)(w0 / sum);
        g[idx[1]] = (float)(w1 / sum);
        g[idx[2]] = (float)(w2 / sum);
#pragma unroll
        for (int e = 0; e < NE; ++e)
            gates[(size_t)(e * NT + t) * chunk + n0 + nl] = g[e];
    }
}

// ---------------------------------------------------------------------------
// Small utility kernels
// ---------------------------------------------------------------------------
__global__ __launch_bounds__(256) void k_init_out(float* __restrict__ out,
                                                  const float* __restrict__ tb2)
{
    const int i = blockIdx.x * 256 + threadIdx.x;
    if (i < NT * NTOK) out[i] = tb2[i >> 14];
}

__global__ __launch_bounds__(256) void k_f32_to_f16(const float* __restrict__ s,
                                                    _Float16* __restrict__ d, int n)
{
    const int i = blockIdx.x * 256 + threadIdx.x;
    if (i < n) d[i] = (_Float16)s[i];
}

// transpose+convert one DH x DH fp32 [K][M] -> fp16 [M][K]; matrix blockIdx.z
__global__ __launch_bounds__(256) void k_w16t(const float* __restrict__ src,
                                              _Float16* __restrict__ dst)
{
    __shared__ float t[32][33];
    const float* s = src + (size_t)blockIdx.z * DH * DH;
    _Float16* d    = dst + (size_t)blockIdx.z * DH * DH;
    const int k0 = blockIdx.x * 32, m0 = blockIdx.y * 32;
    const int tx = threadIdx.x & 31, ty = threadIdx.x >> 5;   // ty 0..7
    for (int r = ty; r < 32; r += 8)
        t[r][tx] = s[(size_t)(k0 + r) * DH + m0 + tx];
    __syncthreads();
    for (int r = ty; r < 32; r += 8)
        d[(size_t)(m0 + r) * DH + k0 + tx] = (_Float16)t[tx][r];
}

// ---------------------------------------------------------------------------
extern "C" void kernel_launch(void* const* d_in, const int* in_sizes, int n_in,
                              void* d_out, int out_size, void* d_ws, size_t ws_size,
                              hipStream_t stream)
{
    const float* x      = (const float*)d_in[0];
    const float* fc1_w  = (const float*)d_in[1];
    const float* fc1_b  = (const float*)d_in[2];
    const float* fc2_w  = (const float*)d_in[3];
    const float* fc2_b  = (const float*)d_in[4];
    const float* w_gate = (const float*)d_in[5];
    const float* ew1    = (const float*)d_in[6];
    const float* eb1    = (const float*)d_in[7];
    const float* ew2    = (const float*)d_in[8];
    const float* eb2    = (const float*)d_in[9];
    const float* tw1    = (const float*)d_in[10];
    const float* tb1    = (const float*)d_in[11];
    const float* tw2    = (const float*)d_in[12];
    const float* tb2    = (const float*)d_in[13];
    float* out = (float*)d_out;

    // fixed: fp16-transposed weights (ew1t, ew2t, tw1t) = 15 * DH*DH * 2B
    const size_t fixed = (size_t)15 * DH * DH * 2;
    // per-token: h1(4B*DH) + h32(4B*DH) + gates(72B) + h16/eh16/mo16 (5*DH*2B)
    const size_t per_tok = (size_t)2 * DH * 4 + NE * NT * 4 + (size_t)5 * DH * 2;
    int chunk = 16384;
    while (chunk > 128 && fixed + (size_t)chunk * per_tok > ws_size) chunk >>= 1;

    char* p = (char*)d_ws;
    _Float16* ew1t = (_Float16*)p; p += (size_t)NE * DH * DH * 2;
    _Float16* ew2t = (_Float16*)p; p += (size_t)NE * DH * DH * 2;
    _Float16* tw1t = (_Float16*)p; p += (size_t)NT * DH * DH * 2;
    float* h1    = (float*)p;     p += (size_t)chunk * DH * 4;
    float* h32   = (float*)p;     p += (size_t)chunk * DH * 4;
    float* gates = (float*)p;     p += (size_t)NE * NT * chunk * 4;
    _Float16* h16  = (_Float16*)p; p += (size_t)chunk * DH * 2;
    _Float16* eh16 = (_Float16*)p; p += (size_t)chunk * DH * 2;
    _Float16* mo16 = (_Float16*)p; p += (size_t)NT * chunk * DH * 2;

    const dim3 blk(256);
    const dim3 g64(chunk / 64, DH / 64);
    const dim3 gm(chunk / 128, DH / 128);

    k_init_out<<<dim3((NT * NTOK + 255) / 256), blk, 0, stream>>>(out, tb2);

    // one-time weight convert+transpose to fp16 [M][K]
    k_w16t<<<dim3(32, 32, NE), blk, 0, stream>>>(ew1, ew1t);
    k_w16t<<<dim3(32, 32, NE), blk, 0, stream>>>(ew2, ew2t);
    k_w16t<<<dim3(32, 32, NT), blk, 0, stream>>>(tw1, tw1t);

    for (int nb = 0; nb < NTOK; nb += chunk) {
        const float* xc = x + (size_t)nb * DH;

        // shared bottom (fp64 accumulate -> selection-exact gating)
        k_gemm_bias<double, true ><<<g64, blk, 0, stream>>>(xc, fc1_w, fc1_b, h1,  DH, DH);
        k_gemm_bias<double, false><<<g64, blk, 0, stream>>>(h1, fc2_w, fc2_b, h32, DH, DH);

        k_f32_to_f16<<<dim3((chunk * DH + 255) / 256), blk, 0, stream>>>(h32, h16, chunk * DH);
        k_gating<<<dim3(chunk / 64), blk, 0, stream>>>(h32, w_gate, gates, chunk);

        // experts via fp16 MFMA (serialized -> race-free fp16 mo accumulate)
        for (int e = 0; e < NE; ++e) {
            k_mfma_h16relu<<<gm, blk, 0, stream>>>(
                h16, ew1t + (size_t)e * DH * DH, eb1 + e * DH, eh16);
            k_mfma_combine<<<gm, blk, 0, stream>>>(
                eh16, ew2t + (size_t)e * DH * DH, eb2 + e * DH, gates, mo16, e,
                (e == 0) ? 1 : 0, chunk);
        }

        // towers via fp16 MFMA + fused final dot
        k_mfma_tower<<<dim3(chunk / 128, DH / 128, NT), blk, 0, stream>>>(
            mo16, tw1t, tb1, tw2, out, nb, chunk);
    }
}

// Round 4
// 1913.679 us; speedup vs baseline: 4.8462x; 1.6954x over previous
//
#include <hip/hip_runtime.h>
#include <hip/hip_bf16.h>
#include <math.h>
#include <stdint.h>

#define NTOK 16384   // N = B*C
#define DH   1024    // D = H = EH = TH
#define NE   6       // experts
#define NT   3       // tasks

typedef _Float16 f16x8 __attribute__((ext_vector_type(8)));
typedef float    f32x4 __attribute__((ext_vector_type(4)));

// ---------------------------------------------------------------------------
// global -> LDS staging, 16B per lane, wave-uniform base (lane*16 implicit)
// ---------------------------------------------------------------------------
__device__ __forceinline__ void stage16(const _Float16* g, _Float16* lds_base, int lane)
{
#if __has_builtin(__builtin_amdgcn_global_load_lds)
    __builtin_amdgcn_global_load_lds(
        (const __attribute__((address_space(1))) unsigned int*)(uintptr_t)g,
        (__attribute__((address_space(3))) unsigned int*)(uintptr_t)lds_base, 16, 0, 0);
#else
    *(float4*)(lds_base + lane * 8) = *(const float4*)g;
#endif
}

__device__ __forceinline__ f32x4 mfma16(f16x8 a, f16x8 b, f32x4 c)
{
    return __builtin_amdgcn_mfma_f32_16x16x32_f16(a, b, c, 0, 0, 0);
}

// ---------------------------------------------------------------------------
// fp16 MFMA 128x128 tile core (single precision inputs) — proven in R3.
// A [rows x DH] row-major fp16, Bt [M x DH] row-major fp16 (pre-transposed).
// 256 thr = 4 waves 2x2; wave = 64x64 via 4x4 of 16x16x32.
// ---------------------------------------------------------------------------
__device__ __forceinline__ void mfma_tile(const _Float16* __restrict__ A,
                                          const _Float16* __restrict__ Bt,
                                          int n0, int m0, f32x4 acc[4][4])
{
    __shared__ __align__(16) _Float16 As[128 * 32];
    __shared__ __align__(16) _Float16 Bs[128 * 32];
    const int tid  = threadIdx.x;
    const int w    = tid >> 6, lane = tid & 63;
    const int lr   = lane >> 2;
    const int lk   = (lane & 3) * 8;
    const int wm   = (w >> 1) * 64, wn = (w & 1) * 64;
    const int fl   = lane & 15;
    const int fq   = (lane >> 4) * 8;

    const _Float16* ga0 = A  + (size_t)(n0 + w * 32 + lr) * DH + lk;
    const _Float16* ga1 = ga0 + 16 * DH;
    const _Float16* gb0 = Bt + (size_t)(m0 + w * 32 + lr) * DH + lk;
    const _Float16* gb1 = gb0 + 16 * DH;
    _Float16* la0 = As + (w * 32) * 32;
    _Float16* la1 = la0 + 16 * 32;
    _Float16* lb0 = Bs + (w * 32) * 32;
    _Float16* lb1 = lb0 + 16 * 32;

    for (int ks = 0; ks < DH; ks += 32) {
        __syncthreads();
        stage16(ga0 + ks, la0, lane);
        stage16(ga1 + ks, la1, lane);
        stage16(gb0 + ks, lb0, lane);
        stage16(gb1 + ks, lb1, lane);
        __syncthreads();
        f16x8 af[4], bf[4];
#pragma unroll
        for (int i = 0; i < 4; ++i)
            af[i] = *(const f16x8*)(As + (wm + i * 16 + fl) * 32 + fq);
#pragma unroll
        for (int j = 0; j < 4; ++j)
            bf[j] = *(const f16x8*)(Bs + (wn + j * 16 + fl) * 32 + fq);
#pragma unroll
        for (int i = 0; i < 4; ++i)
#pragma unroll
            for (int j = 0; j < 4; ++j)
                acc[i][j] = mfma16(af[i], bf[j], acc[i][j]);
    }
}

// ---------------------------------------------------------------------------
// Split-fp16 (hi+lo) MFMA tile: acc += Ahi*Bhi + Ahi*Blo + Alo*Bhi.
// fp32-accuracy GEMM at MFMA rate (error ~2^-22 rel; np fp32 ref is ~2^-21).
// ---------------------------------------------------------------------------
__device__ __forceinline__ void mfma_tile_split(const _Float16* __restrict__ Ah,
                                                const _Float16* __restrict__ Al,
                                                const _Float16* __restrict__ Bh,
                                                const _Float16* __restrict__ Bl,
                                                int n0, int m0, f32x4 acc[4][4])
{
    __shared__ __align__(16) _Float16 Ash[128 * 32];
    __shared__ __align__(16) _Float16 Asl[128 * 32];
    __shared__ __align__(16) _Float16 Bsh[128 * 32];
    __shared__ __align__(16) _Float16 Bsl[128 * 32];
    const int tid  = threadIdx.x;
    const int w    = tid >> 6, lane = tid & 63;
    const int lr   = lane >> 2;
    const int lk   = (lane & 3) * 8;
    const int wm   = (w >> 1) * 64, wn = (w & 1) * 64;
    const int fl   = lane & 15;
    const int fq   = (lane >> 4) * 8;

    const size_t ro = (size_t)(n0 + w * 32 + lr) * DH + lk;
    const size_t co = (size_t)(m0 + w * 32 + lr) * DH + lk;
    const int lo0 = (w * 32) * 32, lo1 = lo0 + 16 * 32;

    for (int ks = 0; ks < DH; ks += 32) {
        __syncthreads();
        stage16(Ah + ro + ks,            Ash + lo0, lane);
        stage16(Ah + ro + 16 * DH + ks,  Ash + lo1, lane);
        stage16(Al + ro + ks,            Asl + lo0, lane);
        stage16(Al + ro + 16 * DH + ks,  Asl + lo1, lane);
        stage16(Bh + co + ks,            Bsh + lo0, lane);
        stage16(Bh + co + 16 * DH + ks,  Bsh + lo1, lane);
        stage16(Bl + co + ks,            Bsl + lo0, lane);
        stage16(Bl + co + 16 * DH + ks,  Bsl + lo1, lane);
        __syncthreads();
        f16x8 ah[4], al[4], bh[4], bl[4];
#pragma unroll
        for (int i = 0; i < 4; ++i) {
            const int off = (wm + i * 16 + fl) * 32 + fq;
            ah[i] = *(const f16x8*)(Ash + off);
            al[i] = *(const f16x8*)(Asl + off);
        }
#pragma unroll
        for (int j = 0; j < 4; ++j) {
            const int off = (wn + j * 16 + fl) * 32 + fq;
            bh[j] = *(const f16x8*)(Bsh + off);
            bl[j] = *(const f16x8*)(Bsl + off);
        }
#pragma unroll
        for (int i = 0; i < 4; ++i)
#pragma unroll
            for (int j = 0; j < 4; ++j) {
                acc[i][j] = mfma16(al[i], bh[j], acc[i][j]);
                acc[i][j] = mfma16(ah[i], bl[j], acc[i][j]);
                acc[i][j] = mfma16(ah[i], bh[j], acc[i][j]);
            }
    }
}

// C/D layout: col = wn + j*16 + (lane&15); row = wm + i*16 + (lane>>4)*4 + reg.

// ---------------------------------------------------------------------------
// fc1: h1 = relu(x@w1 + b1), output as split fp16 pair (hi, lo)
// ---------------------------------------------------------------------------
__global__ __launch_bounds__(256) void k_fc1(const _Float16* __restrict__ xh,
                                             const _Float16* __restrict__ xl,
                                             const _Float16* __restrict__ wh,
                                             const _Float16* __restrict__ wl,
                                             const float* __restrict__ bias,
                                             _Float16* __restrict__ oh,
                                             _Float16* __restrict__ ol)
{
    f32x4 acc[4][4] = {};
    const int n0 = blockIdx.x * 128, m0 = blockIdx.y * 128;
    mfma_tile_split(xh, xl, wh, wl, n0, m0, acc);
    const int lane = threadIdx.x & 63, w = threadIdx.x >> 6;
    const int wm = (w >> 1) * 64, wn = (w & 1) * 64;
    const int fl = lane & 15, quad = lane >> 4;
#pragma unroll
    for (int i = 0; i < 4; ++i)
#pragma unroll
        for (int reg = 0; reg < 4; ++reg) {
            const int r = n0 + wm + i * 16 + quad * 4 + reg;
#pragma unroll
            for (int j = 0; j < 4; ++j) {
                const int c = m0 + wn + j * 16 + fl;
                const float v = fmaxf(acc[i][j][reg] + bias[c], 0.0f);
                const _Float16 h = (_Float16)v;
                oh[(size_t)r * DH + c] = h;
                ol[(size_t)r * DH + c] = (_Float16)(v - (float)h);
            }
        }
}

// ---------------------------------------------------------------------------
// fc2: h = h1@w2 + b2, output fp32 (for fp64 gating) + fp16 (for experts)
// ---------------------------------------------------------------------------
__global__ __launch_bounds__(256) void k_fc2(const _Float16* __restrict__ ah,
                                             const _Float16* __restrict__ al,
                                             const _Float16* __restrict__ wh,
                                             const _Float16* __restrict__ wl,
                                             const float* __restrict__ bias,
                                             float* __restrict__ h32,
                                             _Float16* __restrict__ h16)
{
    f32x4 acc[4][4] = {};
    const int n0 = blockIdx.x * 128, m0 = blockIdx.y * 128;
    mfma_tile_split(ah, al, wh, wl, n0, m0, acc);
    const int lane = threadIdx.x & 63, w = threadIdx.x >> 6;
    const int wm = (w >> 1) * 64, wn = (w & 1) * 64;
    const int fl = lane & 15, quad = lane >> 4;
#pragma unroll
    for (int i = 0; i < 4; ++i)
#pragma unroll
        for (int reg = 0; reg < 4; ++reg) {
            const int r = n0 + wm + i * 16 + quad * 4 + reg;
#pragma unroll
            for (int j = 0; j < 4; ++j) {
                const int c = m0 + wn + j * 16 + fl;
                const float v = acc[i][j][reg] + bias[c];
                h32[(size_t)r * DH + c] = v;
                h16[(size_t)r * DH + c] = (_Float16)v;
            }
        }
}

// ---------------------------------------------------------------------------
// Expert layer 1: eh16 = fp16(relu(A@Bt^T + bias))
// ---------------------------------------------------------------------------
__global__ __launch_bounds__(256) void k_mfma_h16relu(const _Float16* __restrict__ A,
                                                      const _Float16* __restrict__ Bt,
                                                      const float* __restrict__ bias,
                                                      _Float16* __restrict__ C)
{
    f32x4 acc[4][4] = {};
    const int n0 = blockIdx.x * 128, m0 = blockIdx.y * 128;
    mfma_tile(A, Bt, n0, m0, acc);
    const int lane = threadIdx.x & 63, w = threadIdx.x >> 6;
    const int wm = (w >> 1) * 64, wn = (w & 1) * 64;
    const int fl = lane & 15, quad = lane >> 4;
#pragma unroll
    for (int i = 0; i < 4; ++i)
#pragma unroll
        for (int reg = 0; reg < 4; ++reg) {
            const int r = n0 + wm + i * 16 + quad * 4 + reg;
#pragma unroll
            for (int j = 0; j < 4; ++j) {
                const int c = m0 + wn + j * 16 + fl;
                C[(size_t)r * DH + c] = (_Float16)fmaxf(acc[i][j][reg] + bias[c], 0.0f);
            }
        }
}

// ---------------------------------------------------------------------------
// Expert layer 2 + gated combine into fp16 mo (experts serialized -> no race)
// ---------------------------------------------------------------------------
__global__ __launch_bounds__(256) void k_mfma_combine(const _Float16* __restrict__ A,
                                                      const _Float16* __restrict__ Bt,
                                                      const float* __restrict__ bias,
                                                      const float* __restrict__ gates, // [E][T][chunk]
                                                      _Float16* __restrict__ mo,       // [T][chunk][DH]
                                                      int e, int first, int chunk)
{
    f32x4 acc[4][4] = {};
    const int n0 = blockIdx.x * 128, m0 = blockIdx.y * 128;
    mfma_tile(A, Bt, n0, m0, acc);
    const int lane = threadIdx.x & 63, w = threadIdx.x >> 6;
    const int wm = (w >> 1) * 64, wn = (w & 1) * 64;
    const int fl = lane & 15, quad = lane >> 4;
#pragma unroll
    for (int i = 0; i < 4; ++i)
#pragma unroll
        for (int reg = 0; reg < 4; ++reg) {
            const int r = n0 + wm + i * 16 + quad * 4 + reg;
            const float g0 = gates[(size_t)(e * NT + 0) * chunk + r];
            const float g1 = gates[(size_t)(e * NT + 1) * chunk + r];
            const float g2 = gates[(size_t)(e * NT + 2) * chunk + r];
#pragma unroll
            for (int j = 0; j < 4; ++j) {
                const int c = m0 + wn + j * 16 + fl;
                const float v = acc[i][j][reg] + bias[c];
                const size_t o0 = ((size_t)0 * chunk + r) * DH + c;
                const size_t o1 = ((size_t)1 * chunk + r) * DH + c;
                const size_t o2 = ((size_t)2 * chunk + r) * DH + c;
                if (first) {
                    mo[o0] = (_Float16)(g0 * v);
                    mo[o1] = (_Float16)(g1 * v);
                    mo[o2] = (_Float16)(g2 * v);
                } else {
                    mo[o0] = (_Float16)((float)mo[o0] + g0 * v);
                    mo[o1] = (_Float16)((float)mo[o1] + g1 * v);
                    mo[o2] = (_Float16)((float)mo[o2] + g2 * v);
                }
            }
        }
}

// ---------------------------------------------------------------------------
// Tower: th = relu(mo[t]@tw1t[t]^T + tb1[t]); out[t][n] += th . tw2[t]
// ---------------------------------------------------------------------------
__global__ __launch_bounds__(256) void k_mfma_tower(const _Float16* __restrict__ mo,
                                                    const _Float16* __restrict__ tw1t,
                                                    const float* __restrict__ tb1,
                                                    const float* __restrict__ tw2,
                                                    float* __restrict__ out,
                                                    int n_base, int chunk)
{
    const int t = blockIdx.z;
    const _Float16* A  = mo   + (size_t)t * chunk * DH;
    const _Float16* Bt = tw1t + (size_t)t * DH * DH;
    const float* b1 = tb1 + t * DH;
    const float* w2 = tw2 + t * DH;

    f32x4 acc[4][4] = {};
    const int n0 = blockIdx.x * 128, m0 = blockIdx.y * 128;
    mfma_tile(A, Bt, n0, m0, acc);
    const int lane = threadIdx.x & 63, w = threadIdx.x >> 6;
    const int wm = (w >> 1) * 64, wn = (w & 1) * 64;
    const int fl = lane & 15, quad = lane >> 4;

    float s[4][4];
#pragma unroll
    for (int i = 0; i < 4; ++i)
#pragma unroll
        for (int reg = 0; reg < 4; ++reg) {
            float v = 0.0f;
#pragma unroll
            for (int j = 0; j < 4; ++j) {
                const int c = m0 + wn + j * 16 + fl;
                v += fmaxf(acc[i][j][reg] + b1[c], 0.0f) * w2[c];
            }
            s[i][reg] = v;
        }
#pragma unroll
    for (int d = 8; d > 0; d >>= 1)
#pragma unroll
        for (int i = 0; i < 4; ++i)
#pragma unroll
            for (int reg = 0; reg < 4; ++reg)
                s[i][reg] += __shfl_down(s[i][reg], d, 16);
    if (fl == 0) {
#pragma unroll
        for (int i = 0; i < 4; ++i)
#pragma unroll
            for (int reg = 0; reg < 4; ++reg) {
                const int r = n0 + wm + i * 16 + quad * 4 + reg;
                atomicAdd(out + (size_t)t * NTOK + n_base + r, s[i][reg]);
            }
    }
}

// ---------------------------------------------------------------------------
// Gating (fp64, selection-exact given h32) — unchanged from R2/R3.
// ---------------------------------------------------------------------------
__global__ __launch_bounds__(256) void k_gating(const float* __restrict__ h,
                                                const float* __restrict__ w_gate,
                                                float* __restrict__ gates,
                                                int chunk)
{
    __shared__ float hs[64][17];
    const int tid = threadIdx.x;
    const int n0  = blockIdx.x * 64;
    const int t   = tid >> 6;
    const int nl  = tid & 63;
    const int la_n = tid >> 2;
    const int la_k = (tid & 3) << 2;

    double acc[NE] = {0, 0, 0, 0, 0, 0};
    for (int kc = 0; kc < DH; kc += 16) {
        float4 hv = *(const float4*)(h + (size_t)(n0 + la_n) * DH + kc + la_k);
        __syncthreads();
        hs[la_n][la_k + 0] = hv.x;
        hs[la_n][la_k + 1] = hv.y;
        hs[la_n][la_k + 2] = hv.z;
        hs[la_n][la_k + 3] = hv.w;
        __syncthreads();
        if (t < NT) {
            for (int k = 0; k < 16; ++k) {
                const double hvk = (double)hs[nl][k];
                const float* wg = w_gate + ((size_t)t * DH + kc + k) * NE;
#pragma unroll
                for (int e = 0; e < NE; ++e)
                    acc[e] += hvk * (double)wg[e];
            }
        }
    }
    if (t < NT) {
        bool used[NE] = {false, false, false, false, false, false};
        int idx[3];
        double tv[3];
#pragma unroll
        for (int k = 0; k < 3; ++k) {
            int best = -1;
#pragma unroll
            for (int e = 0; e < NE; ++e)
                if (!used[e] && (best < 0 || acc[e] > acc[best])) best = e;
            used[best] = true;
            idx[k] = best;
            tv[k] = acc[best];
        }
        const double m  = tv[0];
        const double w0 = exp(tv[0] - m), w1 = exp(tv[1] - m), w2 = exp(tv[2] - m);
        const double sum = w0 + w1 + w2;
        float g[NE] = {0.f, 0.f, 0.f, 0.f, 0.f, 0.f};
        g[idx[0]] = (float)(w0 / sum);
        g[idx[1]] = (float)(w1 / sum);
        g[idx[2]] = (float)(w2 / sum);
#pragma unroll
        for (int e = 0; e < NE; ++e)
            gates[(size_t)(e * NT + t) * chunk + n0 + nl] = g[e];
    }
}

// ---------------------------------------------------------------------------
// Utility kernels
// ---------------------------------------------------------------------------
__global__ __launch_bounds__(256) void k_init_out(float* __restrict__ out,
                                                  const float* __restrict__ tb2)
{
    const int i = blockIdx.x * 256 + threadIdx.x;
    if (i < NT * NTOK) out[i] = tb2[i >> 14];
}

// elementwise split fp32 -> (hi, lo) fp16
__global__ __launch_bounds__(256) void k_xsplit(const float* __restrict__ s,
                                                _Float16* __restrict__ hi,
                                                _Float16* __restrict__ lo, int n)
{
    const int i = blockIdx.x * 256 + threadIdx.x;
    if (i < n) {
        const float v = s[i];
        const _Float16 h = (_Float16)v;
        hi[i] = h;
        lo[i] = (_Float16)(v - (float)h);
    }
}

// transpose one DH x DH fp32 [K][M] -> fp16 [M][K]; matrix index blockIdx.z
__global__ __launch_bounds__(256) void k_w16t(const float* __restrict__ src,
                                              _Float16* __restrict__ dst)
{
    __shared__ float t[32][33];
    const float* s = src + (size_t)blockIdx.z * DH * DH;
    _Float16* d    = dst + (size_t)blockIdx.z * DH * DH;
    const int k0 = blockIdx.x * 32, m0 = blockIdx.y * 32;
    const int tx = threadIdx.x & 31, ty = threadIdx.x >> 5;
    for (int r = ty; r < 32; r += 8)
        t[r][tx] = s[(size_t)(k0 + r) * DH + m0 + tx];
    __syncthreads();
    for (int r = ty; r < 32; r += 8)
        d[(size_t)(m0 + r) * DH + k0 + tx] = (_Float16)t[tx][r];
}

// transpose + split one DH x DH fp32 [K][M] -> fp16 hi/lo [M][K]
__global__ __launch_bounds__(256) void k_wsplit_t(const float* __restrict__ src,
                                                  _Float16* __restrict__ dhi,
                                                  _Float16* __restrict__ dlo)
{
    __shared__ float t[32][33];
    const int k0 = blockIdx.x * 32, m0 = blockIdx.y * 32;
    const int tx = threadIdx.x & 31, ty = threadIdx.x >> 5;
    for (int r = ty; r < 32; r += 8)
        t[r][tx] = src[(size_t)(k0 + r) * DH + m0 + tx];
    __syncthreads();
    for (int r = ty; r < 32; r += 8) {
        const float v = t[tx][r];
        const _Float16 h = (_Float16)v;
        dhi[(size_t)(m0 + r) * DH + k0 + tx] = h;
        dlo[(size_t)(m0 + r) * DH + k0 + tx] = (_Float16)(v - (float)h);
    }
}

// ---------------------------------------------------------------------------
extern "C" void kernel_launch(void* const* d_in, const int* in_sizes, int n_in,
                              void* d_out, int out_size, void* d_ws, size_t ws_size,
                              hipStream_t stream)
{
    const float* x      = (const float*)d_in[0];
    const float* fc1_w  = (const float*)d_in[1];
    const float* fc1_b  = (const float*)d_in[2];
    const float* fc2_w  = (const float*)d_in[3];
    const float* fc2_b  = (const float*)d_in[4];
    const float* w_gate = (const float*)d_in[5];
    const float* ew1    = (const float*)d_in[6];
    const float* eb1    = (const float*)d_in[7];
    const float* ew2    = (const float*)d_in[8];
    const float* eb2    = (const float*)d_in[9];
    const float* tw1    = (const float*)d_in[10];
    const float* tb1    = (const float*)d_in[11];
    const float* tw2    = (const float*)d_in[12];
    const float* tb2    = (const float*)d_in[13];
    float* out = (float*)d_out;

    // fixed: 15 fp16 weight planes (ew1t,ew2t,tw1t) + 4 split fc planes
    const size_t plane = (size_t)DH * DH * 2;           // 2 MiB
    const size_t fixed = 19 * plane;
    // per-token: 9 fp16 planes (xh,xl,h1h,h1l,h16,eh16,mo*3) + h32 fp32 + gates
    const size_t per_tok = (size_t)9 * DH * 2 + (size_t)DH * 4 + NE * NT * 4;
    int chunk = 16384;
    while (chunk > 128 && fixed + (size_t)chunk * per_tok > ws_size) chunk >>= 1;

    char* p = (char*)d_ws;
    _Float16* ew1t = (_Float16*)p; p += NE * plane;
    _Float16* ew2t = (_Float16*)p; p += NE * plane;
    _Float16* tw1t = (_Float16*)p; p += NT * plane;
    _Float16* w1th = (_Float16*)p; p += plane;
    _Float16* w1tl = (_Float16*)p; p += plane;
    _Float16* w2th = (_Float16*)p; p += plane;
    _Float16* w2tl = (_Float16*)p; p += plane;
    _Float16* xh   = (_Float16*)p; p += (size_t)chunk * DH * 2;
    _Float16* xl   = (_Float16*)p; p += (size_t)chunk * DH * 2;
    _Float16* h1h  = (_Float16*)p; p += (size_t)chunk * DH * 2;
    _Float16* h1l  = (_Float16*)p; p += (size_t)chunk * DH * 2;
    _Float16* h16  = (_Float16*)p; p += (size_t)chunk * DH * 2;
    _Float16* eh16 = (_Float16*)p; p += (size_t)chunk * DH * 2;
    _Float16* mo16 = (_Float16*)p; p += (size_t)NT * chunk * DH * 2;
    float* h32     = (float*)p;    p += (size_t)chunk * DH * 4;
    float* gates   = (float*)p;    p += (size_t)NE * NT * chunk * 4;

    const dim3 blk(256);
    const dim3 gm(chunk / 128, DH / 128);

    k_init_out<<<dim3((NT * NTOK + 255) / 256), blk, 0, stream>>>(out, tb2);

    // one-time weight prep
    k_w16t<<<dim3(32, 32, NE), blk, 0, stream>>>(ew1, ew1t);
    k_w16t<<<dim3(32, 32, NE), blk, 0, stream>>>(ew2, ew2t);
    k_w16t<<<dim3(32, 32, NT), blk, 0, stream>>>(tw1, tw1t);
    k_wsplit_t<<<dim3(32, 32), blk, 0, stream>>>(fc1_w, w1th, w1tl);
    k_wsplit_t<<<dim3(32, 32), blk, 0, stream>>>(fc2_w, w2th, w2tl);

    for (int nb = 0; nb < NTOK; nb += chunk) {
        const float* xc = x + (size_t)nb * DH;
        const int nel = chunk * DH;

        // shared bottom via split-fp16 MFMA (fp32-accurate -> selection-safe)
        k_xsplit<<<dim3((nel + 255) / 256), blk, 0, stream>>>(xc, xh, xl, nel);
        k_fc1<<<gm, blk, 0, stream>>>(xh, xl, w1th, w1tl, fc1_b, h1h, h1l);
        k_fc2<<<gm, blk, 0, stream>>>(h1h, h1l, w2th, w2tl, fc2_b, h32, h16);

        // gating (fp64 on fp32 h)
        k_gating<<<dim3(chunk / 64), blk, 0, stream>>>(h32, w_gate, gates, chunk);

        // experts via fp16 MFMA (serialized -> race-free fp16 mo accumulate)
        for (int e = 0; e < NE; ++e) {
            k_mfma_h16relu<<<gm, blk, 0, stream>>>(
                h16, ew1t + (size_t)e * DH * DH, eb1 + e * DH, eh16);
            k_mfma_combine<<<gm, blk, 0, stream>>>(
                eh16, ew2t + (size_t)e * DH * DH, eb2 + e * DH, gates, mo16, e,
                (e == 0) ? 1 : 0, chunk);
        }

        // towers via fp16 MFMA + fused final dot
        k_mfma_tower<<<dim3(chunk / 128, DH / 128, NT), blk, 0, stream>>>(
            mo16, tw1t, tb1, tw2, out, nb, chunk);
    }
}

// Round 5
// 1466.547 us; speedup vs baseline: 6.3238x; 1.3049x over previous
//
#include <hip/hip_runtime.h>
#include <hip/hip_bf16.h>
#include <math.h>
#include <stdint.h>

#define NTOK 16384   // N = B*C
#define DH   1024    // D = H = EH = TH
#define NE   6       // experts
#define NT   3       // tasks

typedef _Float16 f16x8 __attribute__((ext_vector_type(8)));
typedef float    f32x4 __attribute__((ext_vector_type(4)));

// ---------------------------------------------------------------------------
// global -> LDS staging, 16B per lane, wave-uniform base (lane*16 implicit)
// ---------------------------------------------------------------------------
__device__ __forceinline__ void stage16(const _Float16* g, _Float16* lds_base, int lane)
{
#if __has_builtin(__builtin_amdgcn_global_load_lds)
    __builtin_amdgcn_global_load_lds(
        (const __attribute__((address_space(1))) unsigned int*)(uintptr_t)g,
        (__attribute__((address_space(3))) unsigned int*)(uintptr_t)lds_base, 16, 0, 0);
#else
    *(float4*)(lds_base + lane * 8) = *(const float4*)g;
#endif
}

__device__ __forceinline__ f32x4 mfma16(f16x8 a, f16x8 b, f32x4 c)
{
    return __builtin_amdgcn_mfma_f32_16x16x32_f16(a, b, c, 0, 0, 0);
}

// ---------------------------------------------------------------------------
// fp16 MFMA 128x128 tile core. A [rows x DH] fp16, Bt [M x DH] fp16 (pre-T).
// 256 thr = 4 waves 2x2; wave = 64x64 via 4x4 of 16x16x32.
// ---------------------------------------------------------------------------
__device__ __forceinline__ void mfma_tile(const _Float16* __restrict__ A,
                                          const _Float16* __restrict__ Bt,
                                          int n0, int m0, f32x4 acc[4][4])
{
    __shared__ __align__(16) _Float16 As[128 * 32];
    __shared__ __align__(16) _Float16 Bs[128 * 32];
    const int tid  = threadIdx.x;
    const int w    = tid >> 6, lane = tid & 63;
    const int lr   = lane >> 2;
    const int lk   = (lane & 3) * 8;
    const int wm   = (w >> 1) * 64, wn = (w & 1) * 64;
    const int fl   = lane & 15;
    const int fq   = (lane >> 4) * 8;

    const _Float16* ga0 = A  + (size_t)(n0 + w * 32 + lr) * DH + lk;
    const _Float16* ga1 = ga0 + 16 * DH;
    const _Float16* gb0 = Bt + (size_t)(m0 + w * 32 + lr) * DH + lk;
    const _Float16* gb1 = gb0 + 16 * DH;
    _Float16* la0 = As + (w * 32) * 32;
    _Float16* la1 = la0 + 16 * 32;
    _Float16* lb0 = Bs + (w * 32) * 32;
    _Float16* lb1 = lb0 + 16 * 32;

    for (int ks = 0; ks < DH; ks += 32) {
        __syncthreads();
        stage16(ga0 + ks, la0, lane);
        stage16(ga1 + ks, la1, lane);
        stage16(gb0 + ks, lb0, lane);
        stage16(gb1 + ks, lb1, lane);
        __syncthreads();
        f16x8 af[4], bf[4];
#pragma unroll
        for (int i = 0; i < 4; ++i)
            af[i] = *(const f16x8*)(As + (wm + i * 16 + fl) * 32 + fq);
#pragma unroll
        for (int j = 0; j < 4; ++j)
            bf[j] = *(const f16x8*)(Bs + (wn + j * 16 + fl) * 32 + fq);
#pragma unroll
        for (int i = 0; i < 4; ++i)
#pragma unroll
            for (int j = 0; j < 4; ++j)
                acc[i][j] = mfma16(af[i], bf[j], acc[i][j]);
    }
}

// ---------------------------------------------------------------------------
// Split-fp16 (hi+lo) MFMA tile: acc += Ahi*Bhi + Ahi*Blo + Alo*Bhi.
// fp32-accuracy GEMM at MFMA rate (err ~2^-22 rel; np fp32 ref is ~2^-21).
// ---------------------------------------------------------------------------
__device__ __forceinline__ void mfma_tile_split(const _Float16* __restrict__ Ah,
                                                const _Float16* __restrict__ Al,
                                                const _Float16* __restrict__ Bh,
                                                const _Float16* __restrict__ Bl,
                                                int n0, int m0, f32x4 acc[4][4])
{
    __shared__ __align__(16) _Float16 Ash[128 * 32];
    __shared__ __align__(16) _Float16 Asl[128 * 32];
    __shared__ __align__(16) _Float16 Bsh[128 * 32];
    __shared__ __align__(16) _Float16 Bsl[128 * 32];
    const int tid  = threadIdx.x;
    const int w    = tid >> 6, lane = tid & 63;
    const int lr   = lane >> 2;
    const int lk   = (lane & 3) * 8;
    const int wm   = (w >> 1) * 64, wn = (w & 1) * 64;
    const int fl   = lane & 15;
    const int fq   = (lane >> 4) * 8;

    const size_t ro = (size_t)(n0 + w * 32 + lr) * DH + lk;
    const size_t co = (size_t)(m0 + w * 32 + lr) * DH + lk;
    const int lo0 = (w * 32) * 32, lo1 = lo0 + 16 * 32;

    for (int ks = 0; ks < DH; ks += 32) {
        __syncthreads();
        stage16(Ah + ro + ks,            Ash + lo0, lane);
        stage16(Ah + ro + 16 * DH + ks,  Ash + lo1, lane);
        stage16(Al + ro + ks,            Asl + lo0, lane);
        stage16(Al + ro + 16 * DH + ks,  Asl + lo1, lane);
        stage16(Bh + co + ks,            Bsh + lo0, lane);
        stage16(Bh + co + 16 * DH + ks,  Bsh + lo1, lane);
        stage16(Bl + co + ks,            Bsl + lo0, lane);
        stage16(Bl + co + 16 * DH + ks,  Bsl + lo1, lane);
        __syncthreads();
        f16x8 ah[4], al[4], bh[4], bl[4];
#pragma unroll
        for (int i = 0; i < 4; ++i) {
            const int off = (wm + i * 16 + fl) * 32 + fq;
            ah[i] = *(const f16x8*)(Ash + off);
            al[i] = *(const f16x8*)(Asl + off);
        }
#pragma unroll
        for (int j = 0; j < 4; ++j) {
            const int off = (wn + j * 16 + fl) * 32 + fq;
            bh[j] = *(const f16x8*)(Bsh + off);
            bl[j] = *(const f16x8*)(Bsl + off);
        }
#pragma unroll
        for (int i = 0; i < 4; ++i)
#pragma unroll
            for (int j = 0; j < 4; ++j) {
                acc[i][j] = mfma16(al[i], bh[j], acc[i][j]);
                acc[i][j] = mfma16(ah[i], bl[j], acc[i][j]);
                acc[i][j] = mfma16(ah[i], bh[j], acc[i][j]);
            }
    }
}

// C/D layout: col = wn + j*16 + (lane&15); row = wm + i*16 + (lane>>4)*4 + reg.

// ---------------------------------------------------------------------------
// fc1: h1 = relu(x@w1 + b1), output as split fp16 pair (hi, lo)
// ---------------------------------------------------------------------------
__global__ __launch_bounds__(256) void k_fc1(const _Float16* __restrict__ xh,
                                             const _Float16* __restrict__ xl,
                                             const _Float16* __restrict__ wh,
                                             const _Float16* __restrict__ wl,
                                             const float* __restrict__ bias,
                                             _Float16* __restrict__ oh,
                                             _Float16* __restrict__ ol)
{
    f32x4 acc[4][4] = {};
    const int n0 = blockIdx.x * 128, m0 = blockIdx.y * 128;
    mfma_tile_split(xh, xl, wh, wl, n0, m0, acc);
    const int lane = threadIdx.x & 63, w = threadIdx.x >> 6;
    const int wm = (w >> 1) * 64, wn = (w & 1) * 64;
    const int fl = lane & 15, quad = lane >> 4;
#pragma unroll
    for (int i = 0; i < 4; ++i)
#pragma unroll
        for (int reg = 0; reg < 4; ++reg) {
            const int r = n0 + wm + i * 16 + quad * 4 + reg;
#pragma unroll
            for (int j = 0; j < 4; ++j) {
                const int c = m0 + wn + j * 16 + fl;
                const float v = fmaxf(acc[i][j][reg] + bias[c], 0.0f);
                const _Float16 h = (_Float16)v;
                oh[(size_t)r * DH + c] = h;
                ol[(size_t)r * DH + c] = (_Float16)(v - (float)h);
            }
        }
}

// ---------------------------------------------------------------------------
// fc2: h = h1@w2 + b2, output fp32 (for fp64 gating) + fp16 (for experts)
// ---------------------------------------------------------------------------
__global__ __launch_bounds__(256) void k_fc2(const _Float16* __restrict__ ah,
                                             const _Float16* __restrict__ al,
                                             const _Float16* __restrict__ wh,
                                             const _Float16* __restrict__ wl,
                                             const float* __restrict__ bias,
                                             float* __restrict__ h32,
                                             _Float16* __restrict__ h16)
{
    f32x4 acc[4][4] = {};
    const int n0 = blockIdx.x * 128, m0 = blockIdx.y * 128;
    mfma_tile_split(ah, al, wh, wl, n0, m0, acc);
    const int lane = threadIdx.x & 63, w = threadIdx.x >> 6;
    const int wm = (w >> 1) * 64, wn = (w & 1) * 64;
    const int fl = lane & 15, quad = lane >> 4;
#pragma unroll
    for (int i = 0; i < 4; ++i)
#pragma unroll
        for (int reg = 0; reg < 4; ++reg) {
            const int r = n0 + wm + i * 16 + quad * 4 + reg;
#pragma unroll
            for (int j = 0; j < 4; ++j) {
                const int c = m0 + wn + j * 16 + fl;
                const float v = acc[i][j][reg] + bias[c];
                h32[(size_t)r * DH + c] = v;
                h16[(size_t)r * DH + c] = (_Float16)v;
            }
        }
}

// ---------------------------------------------------------------------------
// Expert layer 1, all experts in one dispatch (z = e):
//   eh[e] = fp16(relu(h16 @ ew1t[e]^T + eb1[e]))
// ---------------------------------------------------------------------------
__global__ __launch_bounds__(256) void k_expert1(const _Float16* __restrict__ A,
                                                 const _Float16* __restrict__ ew1t,
                                                 const float* __restrict__ eb1,
                                                 _Float16* __restrict__ eh,
                                                 int chunk)
{
    const int e = blockIdx.z;
    const _Float16* Bt = ew1t + (size_t)e * DH * DH;
    const float* bias  = eb1 + e * DH;
    _Float16* C        = eh + (size_t)e * chunk * DH;

    f32x4 acc[4][4] = {};
    const int n0 = blockIdx.x * 128, m0 = blockIdx.y * 128;
    mfma_tile(A, Bt, n0, m0, acc);
    const int lane = threadIdx.x & 63, w = threadIdx.x >> 6;
    const int wm = (w >> 1) * 64, wn = (w & 1) * 64;
    const int fl = lane & 15, quad = lane >> 4;
#pragma unroll
    for (int i = 0; i < 4; ++i)
#pragma unroll
        for (int reg = 0; reg < 4; ++reg) {
            const int r = n0 + wm + i * 16 + quad * 4 + reg;
#pragma unroll
            for (int j = 0; j < 4; ++j) {
                const int c = m0 + wn + j * 16 + fl;
                C[(size_t)r * DH + c] = (_Float16)fmaxf(acc[i][j][reg] + bias[c], 0.0f);
            }
        }
}

// ---------------------------------------------------------------------------
// Expert layer 2, all experts in one dispatch (z = e):
//   eo[e] = fp16(eh[e] @ ew2t[e]^T + eb2[e])
// ---------------------------------------------------------------------------
__global__ __launch_bounds__(256) void k_expert2(const _Float16* __restrict__ eh,
                                                 const _Float16* __restrict__ ew2t,
                                                 const float* __restrict__ eb2,
                                                 _Float16* __restrict__ eo,
                                                 int chunk)
{
    const int e = blockIdx.z;
    const _Float16* A  = eh + (size_t)e * chunk * DH;
    const _Float16* Bt = ew2t + (size_t)e * DH * DH;
    const float* bias  = eb2 + e * DH;
    _Float16* C        = eo + (size_t)e * chunk * DH;

    f32x4 acc[4][4] = {};
    const int n0 = blockIdx.x * 128, m0 = blockIdx.y * 128;
    mfma_tile(A, Bt, n0, m0, acc);
    const int lane = threadIdx.x & 63, w = threadIdx.x >> 6;
    const int wm = (w >> 1) * 64, wn = (w & 1) * 64;
    const int fl = lane & 15, quad = lane >> 4;
#pragma unroll
    for (int i = 0; i < 4; ++i)
#pragma unroll
        for (int reg = 0; reg < 4; ++reg) {
            const int r = n0 + wm + i * 16 + quad * 4 + reg;
#pragma unroll
            for (int j = 0; j < 4; ++j) {
                const int c = m0 + wn + j * 16 + fl;
                C[(size_t)r * DH + c] = (_Float16)(acc[i][j][reg] + bias[c]);
            }
        }
}

// ---------------------------------------------------------------------------
// Gated combine (elementwise, memory-bound):
//   mo[t][n][:] = sum_e gates[e][t][n] * eo[e][n][:]
// One thread per 8 halfs. fp32 accumulate, single fp16 round.
// ---------------------------------------------------------------------------
__global__ __launch_bounds__(256) void k_combine(const _Float16* __restrict__ eo,
                                                 const float* __restrict__ gates, // [E][T][chunk]
                                                 _Float16* __restrict__ mo,       // [T][chunk][DH]
                                                 int chunk)
{
    const size_t plane = (size_t)chunk * DH;
    const size_t idx = (size_t)blockIdx.x * 256 + threadIdx.x;
    const size_t off = idx * 8;
    if (off >= plane) return;
    const int n = (int)(off / DH);

    float acc[NT][8] = {};
#pragma unroll
    for (int e = 0; e < NE; ++e) {
        const f16x8 v = *(const f16x8*)(eo + e * plane + off);
        float vf[8];
#pragma unroll
        for (int j = 0; j < 8; ++j) vf[j] = (float)v[j];
#pragma unroll
        for (int t = 0; t < NT; ++t) {
            const float g = gates[(size_t)(e * NT + t) * chunk + n];
#pragma unroll
            for (int j = 0; j < 8; ++j) acc[t][j] += g * vf[j];
        }
    }
#pragma unroll
    for (int t = 0; t < NT; ++t) {
        f16x8 r;
#pragma unroll
        for (int j = 0; j < 8; ++j) r[j] = (_Float16)acc[t][j];
        *(f16x8*)(mo + t * plane + off) = r;
    }
}

// ---------------------------------------------------------------------------
// Tower: th = relu(mo[t]@tw1t[t]^T + tb1[t]); out[t][n] += th . tw2[t]
// ---------------------------------------------------------------------------
__global__ __launch_bounds__(256) void k_mfma_tower(const _Float16* __restrict__ mo,
                                                    const _Float16* __restrict__ tw1t,
                                                    const float* __restrict__ tb1,
                                                    const float* __restrict__ tw2,
                                                    float* __restrict__ out,
                                                    int n_base, int chunk)
{
    const int t = blockIdx.z;
    const _Float16* A  = mo   + (size_t)t * chunk * DH;
    const _Float16* Bt = tw1t + (size_t)t * DH * DH;
    const float* b1 = tb1 + t * DH;
    const float* w2 = tw2 + t * DH;

    f32x4 acc[4][4] = {};
    const int n0 = blockIdx.x * 128, m0 = blockIdx.y * 128;
    mfma_tile(A, Bt, n0, m0, acc);
    const int lane = threadIdx.x & 63, w = threadIdx.x >> 6;
    const int wm = (w >> 1) * 64, wn = (w & 1) * 64;
    const int fl = lane & 15, quad = lane >> 4;

    float s[4][4];
#pragma unroll
    for (int i = 0; i < 4; ++i)
#pragma unroll
        for (int reg = 0; reg < 4; ++reg) {
            float v = 0.0f;
#pragma unroll
            for (int j = 0; j < 4; ++j) {
                const int c = m0 + wn + j * 16 + fl;
                v += fmaxf(acc[i][j][reg] + b1[c], 0.0f) * w2[c];
            }
            s[i][reg] = v;
        }
#pragma unroll
    for (int d = 8; d > 0; d >>= 1)
#pragma unroll
        for (int i = 0; i < 4; ++i)
#pragma unroll
            for (int reg = 0; reg < 4; ++reg)
                s[i][reg] += __shfl_down(s[i][reg], d, 16);
    if (fl == 0) {
#pragma unroll
        for (int i = 0; i < 4; ++i)
#pragma unroll
            for (int reg = 0; reg < 4; ++reg) {
                const int r = n0 + wm + i * 16 + quad * 4 + reg;
                atomicAdd(out + (size_t)t * NTOK + n_base + r, s[i][reg]);
            }
    }
}

// ---------------------------------------------------------------------------
// Gating v2: one wave per token. Lane l accumulates k = l+64i over fp64
// wgt[t][e][k] (coalesced), 18 accumulators; xor-butterfly; lanes 0..2
// do top-3 + softmax for task t. Selection-exact (fp64).
// ---------------------------------------------------------------------------
__global__ __launch_bounds__(256) void k_gating2(const float* __restrict__ h,    // [chunk][DH]
                                                 const double* __restrict__ wgt, // [T][E][DH]
                                                 float* __restrict__ gates,      // [E][T][chunk]
                                                 int chunk)
{
    const int w = threadIdx.x >> 6, lane = threadIdx.x & 63;
    const int n = blockIdx.x * 4 + w;

    double acc[NT][NE] = {};
#pragma unroll 4
    for (int i = 0; i < 16; ++i) {
        const int k = lane + 64 * i;
        const double hv = (double)h[(size_t)n * DH + k];
#pragma unroll
        for (int t = 0; t < NT; ++t)
#pragma unroll
            for (int e = 0; e < NE; ++e)
                acc[t][e] += hv * wgt[(size_t)(t * NE + e) * DH + k];
    }
    // butterfly reduce: all lanes end with full sums
#pragma unroll
    for (int d = 1; d < 64; d <<= 1)
#pragma unroll
        for (int t = 0; t < NT; ++t)
#pragma unroll
            for (int e = 0; e < NE; ++e)
                acc[t][e] += __shfl_xor(acc[t][e], d, 64);

    if (lane < NT) {
        const int t = lane;
        double a[NE];
#pragma unroll
        for (int e = 0; e < NE; ++e) a[e] = acc[t][e];
        bool used[NE] = {false, false, false, false, false, false};
        int idx[3];
        double tv[3];
#pragma unroll
        for (int k = 0; k < 3; ++k) {
            int best = -1;
#pragma unroll
            for (int e = 0; e < NE; ++e)
                if (!used[e] && (best < 0 || a[e] > a[best])) best = e;
            used[best] = true;
            idx[k] = best;
            tv[k] = a[best];
        }
        const double m  = tv[0];
        const double w0 = exp(tv[0] - m), w1 = exp(tv[1] - m), w2 = exp(tv[2] - m);
        const double sum = w0 + w1 + w2;
        float g[NE] = {0.f, 0.f, 0.f, 0.f, 0.f, 0.f};
        g[idx[0]] = (float)(w0 / sum);
        g[idx[1]] = (float)(w1 / sum);
        g[idx[2]] = (float)(w2 / sum);
#pragma unroll
        for (int e = 0; e < NE; ++e)
            gates[(size_t)(e * NT + t) * chunk + n] = g[e];
    }
}

// ---------------------------------------------------------------------------
// Utility kernels
// ---------------------------------------------------------------------------
__global__ __launch_bounds__(256) void k_init_out(float* __restrict__ out,
                                                  const float* __restrict__ tb2)
{
    const int i = blockIdx.x * 256 + threadIdx.x;
    if (i < NT * NTOK) out[i] = tb2[i >> 14];
}

__global__ __launch_bounds__(256) void k_xsplit(const float* __restrict__ s,
                                                _Float16* __restrict__ hi,
                                                _Float16* __restrict__ lo, int n)
{
    const int i = blockIdx.x * 256 + threadIdx.x;
    if (i < n) {
        const float v = s[i];
        const _Float16 h = (_Float16)v;
        hi[i] = h;
        lo[i] = (_Float16)(v - (float)h);
    }
}

// transpose one DH x DH fp32 [K][M] -> fp16 [M][K]; matrix index blockIdx.z
__global__ __launch_bounds__(256) void k_w16t(const float* __restrict__ src,
                                              _Float16* __restrict__ dst)
{
    __shared__ float t[32][33];
    const float* s = src + (size_t)blockIdx.z * DH * DH;
    _Float16* d    = dst + (size_t)blockIdx.z * DH * DH;
    const int k0 = blockIdx.x * 32, m0 = blockIdx.y * 32;
    const int tx = threadIdx.x & 31, ty = threadIdx.x >> 5;
    for (int r = ty; r < 32; r += 8)
        t[r][tx] = s[(size_t)(k0 + r) * DH + m0 + tx];
    __syncthreads();
    for (int r = ty; r < 32; r += 8)
        d[(size_t)(m0 + r) * DH + k0 + tx] = (_Float16)t[tx][r];
}

// transpose + split one DH x DH fp32 [K][M] -> fp16 hi/lo [M][K]
__global__ __launch_bounds__(256) void k_wsplit_t(const float* __restrict__ src,
                                                  _Float16* __restrict__ dhi,
                                                  _Float16* __restrict__ dlo)
{
    __shared__ float t[32][33];
    const int k0 = blockIdx.x * 32, m0 = blockIdx.y * 32;
    const int tx = threadIdx.x & 31, ty = threadIdx.x >> 5;
    for (int r = ty; r < 32; r += 8)
        t[r][tx] = src[(size_t)(k0 + r) * DH + m0 + tx];
    __syncthreads();
    for (int r = ty; r < 32; r += 8) {
        const float v = t[tx][r];
        const _Float16 h = (_Float16)v;
        dhi[(size_t)(m0 + r) * DH + k0 + tx] = h;
        dlo[(size_t)(m0 + r) * DH + k0 + tx] = (_Float16)(v - (float)h);
    }
}

// w_gate [T][DH][E] fp32 -> wgt [T][E][DH] fp64
__global__ __launch_bounds__(256) void k_wg_t(const float* __restrict__ wg,
                                              double* __restrict__ wgt)
{
    const int i = blockIdx.x * 256 + threadIdx.x;
    if (i < NT * NE * DH) {
        const int k = i & (DH - 1);
        const int te = i >> 10;          // i / DH
        const int e = te % NE, t = te / NE;
        wgt[i] = (double)wg[((size_t)t * DH + k) * NE + e];
    }
}

// ---------------------------------------------------------------------------
extern "C" void kernel_launch(void* const* d_in, const int* in_sizes, int n_in,
                              void* d_out, int out_size, void* d_ws, size_t ws_size,
                              hipStream_t stream)
{
    const float* x      = (const float*)d_in[0];
    const float* fc1_w  = (const float*)d_in[1];
    const float* fc1_b  = (const float*)d_in[2];
    const float* fc2_w  = (const float*)d_in[3];
    const float* fc2_b  = (const float*)d_in[4];
    const float* w_gate = (const float*)d_in[5];
    const float* ew1    = (const float*)d_in[6];
    const float* eb1    = (const float*)d_in[7];
    const float* ew2    = (const float*)d_in[8];
    const float* eb2    = (const float*)d_in[9];
    const float* tw1    = (const float*)d_in[10];
    const float* tb1    = (const float*)d_in[11];
    const float* tw2    = (const float*)d_in[12];
    const float* tb2    = (const float*)d_in[13];
    float* out = (float*)d_out;

    // fixed: 15 fp16 weight planes (ew1t,ew2t,tw1t) + 4 split fc planes + wgt64
    const size_t plane = (size_t)DH * DH * 2;           // 2 MiB
    const size_t fixed = 19 * plane + (size_t)NT * NE * DH * 8;
    // per-token: eh(6 planes, aliases xh/xl/h1h/h1l/h32) + h16 + eo(6) fp16 + gates
    const size_t per_tok = (size_t)13 * DH * 2 + NE * NT * 4;
    int chunk = 16384;
    while (chunk > 128 && fixed + (size_t)chunk * per_tok > ws_size) chunk >>= 1;

    char* p = (char*)d_ws;
    _Float16* ew1t = (_Float16*)p; p += NE * plane;
    _Float16* ew2t = (_Float16*)p; p += NE * plane;
    _Float16* tw1t = (_Float16*)p; p += NT * plane;
    _Float16* w1th = (_Float16*)p; p += plane;
    _Float16* w1tl = (_Float16*)p; p += plane;
    _Float16* w2th = (_Float16*)p; p += plane;
    _Float16* w2tl = (_Float16*)p; p += plane;
    double* wgt    = (double*)p;   p += (size_t)NT * NE * DH * 8;

    const size_t cpe = (size_t)chunk * DH;     // chunk-plane elements
    _Float16* eh   = (_Float16*)p; p += 6 * cpe * 2;
    _Float16* h16  = (_Float16*)p; p += cpe * 2;
    _Float16* eo   = (_Float16*)p; p += 6 * cpe * 2;
    float* gates   = (float*)p;    p += (size_t)NE * NT * chunk * 4;

    // aliases inside eh (lifetimes end before eh is written by k_expert1)
    _Float16* xh  = eh + 0 * cpe;
    _Float16* xl  = eh + 1 * cpe;
    _Float16* h1h = eh + 2 * cpe;
    _Float16* h1l = eh + 3 * cpe;
    float*    h32 = (float*)(eh + 4 * cpe);    // spans planes 4-5
    _Float16* mo  = eh;                        // 3 planes, written after eh dead

    const dim3 blk(256);
    const dim3 gm(chunk / 128, DH / 128);
    const dim3 gme(chunk / 128, DH / 128, NE);

    k_init_out<<<dim3((NT * NTOK + 255) / 256), blk, 0, stream>>>(out, tb2);

    // one-time weight prep
    k_w16t<<<dim3(32, 32, NE), blk, 0, stream>>>(ew1, ew1t);
    k_w16t<<<dim3(32, 32, NE), blk, 0, stream>>>(ew2, ew2t);
    k_w16t<<<dim3(32, 32, NT), blk, 0, stream>>>(tw1, tw1t);
    k_wsplit_t<<<dim3(32, 32), blk, 0, stream>>>(fc1_w, w1th, w1tl);
    k_wsplit_t<<<dim3(32, 32), blk, 0, stream>>>(fc2_w, w2th, w2tl);
    k_wg_t<<<dim3((NT * NE * DH + 255) / 256), blk, 0, stream>>>(w_gate, wgt);

    for (int nb = 0; nb < NTOK; nb += chunk) {
        const float* xc = x + (size_t)nb * DH;
        const int nel = (int)cpe;

        // shared bottom via split-fp16 MFMA (fp32-accurate -> selection-safe)
        k_xsplit<<<dim3((nel + 255) / 256), blk, 0, stream>>>(xc, xh, xl, nel);
        k_fc1<<<gm, blk, 0, stream>>>(xh, xl, w1th, w1tl, fc1_b, h1h, h1l);
        k_fc2<<<gm, blk, 0, stream>>>(h1h, h1l, w2th, w2tl, fc2_b, h32, h16);

        // gating (fp64, wave-per-token)
        k_gating2<<<dim3(chunk / 4), blk, 0, stream>>>(h32, wgt, gates, chunk);

        // experts: both layers fully parallel over e
        k_expert1<<<gme, blk, 0, stream>>>(h16, ew1t, eb1, eh, chunk);
        k_expert2<<<gme, blk, 0, stream>>>(eh, ew2t, eb2, eo, chunk);

        // gated combine (elementwise) -> mo (reuses eh planes 0-2)
        k_combine<<<dim3((unsigned)((cpe / 8 + 255) / 256)), blk, 0, stream>>>(
            eo, gates, mo, chunk);

        // towers via fp16 MFMA + fused final dot
        k_mfma_tower<<<dim3(chunk / 128, DH / 128, NT), blk, 0, stream>>>(
            mo, tw1t, tb1, tw2, out, nb, chunk);
    }
}